// Round 1
// baseline (4321.932 us; speedup 1.0000x reference)
//
#include <hip/hip_runtime.h>
#include <hip/hip_bf16.h>
#include <math.h>

#define EMBED 1024
#define HEADS 16
#define HDIM 64
#define T_SEQ 4096

// ---------------------------------------------------------------------------
// Generic fp32 tiled GEMM with bias: C[M,N] = A[M,K] @ B[K,N] + bias[N]
// 64x64 tile, 256 threads, 4x4 per-thread micro-tile. M%64==0, N%64==0, K%16==0.
// ---------------------------------------------------------------------------
__global__ __launch_bounds__(256) void gemm_bias(
    const float* __restrict__ A, const float* __restrict__ Bm,
    const float* __restrict__ bias, float* __restrict__ C,
    int M, int N, int K) {
  __shared__ float As[64][17];   // [row][k]  (+1 pad)
  __shared__ float Bs[16][65];   // [k][col]  (+1 pad)
  const int tx = threadIdx.x & 15;       // 0..15 -> col group
  const int ty = threadIdx.x >> 4;       // 0..15 -> row group
  const int brow = blockIdx.y * 64;
  const int bcol = blockIdx.x * 64;

  float acc[4][4];
#pragma unroll
  for (int i = 0; i < 4; ++i)
#pragma unroll
    for (int j = 0; j < 4; ++j) acc[i][j] = 0.f;

  for (int k0 = 0; k0 < K; k0 += 16) {
    // Stage A 64x16 (1024 elems) and B 16x64 (1024 elems); 4 each per thread.
#pragma unroll
    for (int i = threadIdx.x; i < 64 * 16; i += 256) {
      int r = i >> 4, c = i & 15;
      As[r][c] = A[(size_t)(brow + r) * K + (k0 + c)];
    }
#pragma unroll
    for (int i = threadIdx.x; i < 16 * 64; i += 256) {
      int r = i >> 6, c = i & 63;
      Bs[r][c] = Bm[(size_t)(k0 + r) * N + (bcol + c)];
    }
    __syncthreads();
#pragma unroll
    for (int kk = 0; kk < 16; ++kk) {
      float a[4], b[4];
#pragma unroll
      for (int i = 0; i < 4; ++i) a[i] = As[ty * 4 + i][kk];
#pragma unroll
      for (int j = 0; j < 4; ++j) b[j] = Bs[kk][tx * 4 + j];
#pragma unroll
      for (int i = 0; i < 4; ++i)
#pragma unroll
        for (int j = 0; j < 4; ++j) acc[i][j] += a[i] * b[j];
    }
    __syncthreads();
  }

#pragma unroll
  for (int i = 0; i < 4; ++i) {
    int r = brow + ty * 4 + i;
#pragma unroll
    for (int j = 0; j < 4; ++j) {
      int c = bcol + tx * 4 + j;
      C[(size_t)r * N + c] = acc[i][j] + bias[c];
    }
  }
}

// ---------------------------------------------------------------------------
// Causal flash attention, fp32.
// qkv: [T, 3*EMBED] with q at [t][h*64+d], k at [t][1024+h*64+d],
//      v at [t][2048+h*64+d].
// out: [T, EMBED] with out[t][h*64+d]  (i.e. [B,H,T,hd] transposed back).
// Grid: (T/64 q-tiles, HEADS). Block: 256 threads.
// Thread t handles q-row r = t>>2 of the tile and d/k quarter cq = t&3.
// ---------------------------------------------------------------------------
__global__ __launch_bounds__(256) void flash_attn(
    const float* __restrict__ qkv, float* __restrict__ out) {
  const int h = blockIdx.y;
  const int qt = blockIdx.x;
  const int tid = threadIdx.x;
  const int r = tid >> 2;   // q row in tile
  const int cq = tid & 3;   // quarter (16 cols each)

  __shared__ float Qs[64][65];
  __shared__ float Ks[64][65];
  __shared__ float Vs[64][65];
  __shared__ float Ps[64][65];

  const float scale = 0.125f;  // 1/sqrt(64)

  // Load Q tile
  for (int i = tid; i < 64 * 64; i += 256) {
    int rr = i >> 6, dd = i & 63;
    Qs[rr][dd] = qkv[(size_t)(qt * 64 + rr) * (3 * EMBED) + h * HDIM + dd];
  }

  float m = -INFINITY, l = 0.f;
  float o[16];
#pragma unroll
  for (int j = 0; j < 16; ++j) o[j] = 0.f;
  __syncthreads();

  for (int kt = 0; kt <= qt; ++kt) {
    // Stage K,V tiles
    for (int i = tid; i < 64 * 64; i += 256) {
      int rr = i >> 6, dd = i & 63;
      size_t base = (size_t)(kt * 64 + rr) * (3 * EMBED) + h * HDIM + dd;
      Ks[rr][dd] = qkv[base + EMBED];
      Vs[rr][dd] = qkv[base + 2 * EMBED];
    }
    __syncthreads();

    // Scores for this thread: s[j] = Q[r,:] . K[cq*16+j,:]
    float s[16];
#pragma unroll
    for (int j = 0; j < 16; ++j) s[j] = 0.f;
    for (int d = 0; d < 64; ++d) {
      float q = Qs[r][d];
#pragma unroll
      for (int j = 0; j < 16; ++j) s[j] += q * Ks[cq * 16 + j][d];
    }
#pragma unroll
    for (int j = 0; j < 16; ++j) {
      int kcol = cq * 16 + j;
      s[j] *= scale;
      if (kt == qt && kcol > r) s[j] = -INFINITY;
    }

    // Row max across 16 locals, then across the 4 sibling lanes (same wave)
    float mt = s[0];
#pragma unroll
    for (int j = 1; j < 16; ++j) mt = fmaxf(mt, s[j]);
    mt = fmaxf(mt, __shfl_xor(mt, 1));
    mt = fmaxf(mt, __shfl_xor(mt, 2));
    float mnew = fmaxf(m, mt);
    float corr = __expf(m - mnew);  // m=-inf first tile -> 0, mnew finite (col0 valid)

    float lt = 0.f;
#pragma unroll
    for (int j = 0; j < 16; ++j) {
      s[j] = __expf(s[j] - mnew);
      lt += s[j];
    }
    lt += __shfl_xor(lt, 1);
    lt += __shfl_xor(lt, 2);
    l = l * corr + lt;
    m = mnew;

#pragma unroll
    for (int j = 0; j < 16; ++j) Ps[r][cq * 16 + j] = s[j];
#pragma unroll
    for (int j = 0; j < 16; ++j) o[j] *= corr;
    __syncthreads();

    // PV: o[j] (d-col cq*16+j) += sum_k P[r][k] * V[k][cq*16+j]
    for (int k = 0; k < 64; ++k) {
      float p = Ps[r][k];
#pragma unroll
      for (int j = 0; j < 16; ++j) o[j] += p * Vs[k][cq * 16 + j];
    }
    __syncthreads();
  }

  float inv = 1.f / l;
#pragma unroll
  for (int j = 0; j < 16; ++j)
    out[(size_t)(qt * 64 + r) * EMBED + h * HDIM + cq * 16 + j] = o[j] * inv;
}

// ---------------------------------------------------------------------------
extern "C" void kernel_launch(void* const* d_in, const int* in_sizes, int n_in,
                              void* d_out, int out_size, void* d_ws, size_t ws_size,
                              hipStream_t stream) {
  const float* x     = (const float*)d_in[0];   // [1,4096,1024]
  const float* W_qkv = (const float*)d_in[1];   // [1024,3072]
  const float* b_qkv = (const float*)d_in[2];   // [3072]
  const float* W_out = (const float*)d_in[3];   // [1024,1024]
  const float* b_out = (const float*)d_in[4];   // [1024]
  float* out = (float*)d_out;                   // [1,4096,1024]

  float* qkv      = (float*)d_ws;                                   // 48 MB
  float* attn_out = (float*)((char*)d_ws + (size_t)T_SEQ * 3 * EMBED * 4);  // 16 MB

  // 1) QKV projection: [4096,1024] @ [1024,3072] + b
  {
    dim3 grid(3 * EMBED / 64, T_SEQ / 64);
    gemm_bias<<<grid, 256, 0, stream>>>(x, W_qkv, b_qkv, qkv, T_SEQ, 3 * EMBED, EMBED);
  }
  // 2) Causal flash attention
  {
    dim3 grid(T_SEQ / 64, HEADS);
    flash_attn<<<grid, 256, 0, stream>>>(qkv, attn_out);
  }
  // 3) Output projection: [4096,1024] @ [1024,1024] + b
  {
    dim3 grid(EMBED / 64, T_SEQ / 64);
    gemm_bias<<<grid, 256, 0, stream>>>(attn_out, W_out, b_out, out, T_SEQ, EMBED, EMBED);
  }
}

// Round 3
// 297.301 us; speedup vs baseline: 14.5372x; 14.5372x over previous
//
#include <hip/hip_runtime.h>
#include <hip/hip_bf16.h>
#include <math.h>

#define EMBED 1024
#define HEADS 16
#define HDIM 64
#define T_SEQ 4096

typedef __bf16 bf16;
typedef bf16 bf16x8 __attribute__((ext_vector_type(8)));
typedef float f32x4 __attribute__((ext_vector_type(4)));

// ---------------------------------------------------------------------------
// fp32 -> bf16 elementwise (n % 8 == 0)
// ---------------------------------------------------------------------------
__global__ __launch_bounds__(256) void f32_to_bf16(
    const float* __restrict__ in, bf16* __restrict__ out, int n) {
  int i = (blockIdx.x * 256 + threadIdx.x) * 8;
  if (i >= n) return;
  float4 a = *(const float4*)&in[i];
  float4 b = *(const float4*)&in[i + 4];
  bf16x8 o;
  o[0] = (bf16)a.x; o[1] = (bf16)a.y; o[2] = (bf16)a.z; o[3] = (bf16)a.w;
  o[4] = (bf16)b.x; o[5] = (bf16)b.y; o[6] = (bf16)b.z; o[7] = (bf16)b.w;
  *(bf16x8*)&out[i] = o;
}

// ---------------------------------------------------------------------------
// Transpose fp32 [rows][cols] -> bf16 [cols][rows].  rows%32==0, cols%32==0.
// Grid: (cols/32, rows/32), block 256 (32x8).
// ---------------------------------------------------------------------------
__global__ __launch_bounds__(256) void transpose_f32_bf16(
    const float* __restrict__ in, bf16* __restrict__ out, int rows, int cols) {
  __shared__ bf16 t[32][33];
  const int c0 = blockIdx.x * 32, r0 = blockIdx.y * 32;
  const int tx = threadIdx.x & 31, ty = threadIdx.x >> 5;  // ty 0..7
#pragma unroll
  for (int i = 0; i < 4; ++i)
    t[ty + 8 * i][tx] = (bf16)in[(size_t)(r0 + ty + 8 * i) * cols + c0 + tx];
  __syncthreads();
#pragma unroll
  for (int i = 0; i < 4; ++i)
    out[(size_t)(c0 + ty + 8 * i) * rows + r0 + tx] = t[tx][ty + 8 * i];
}

// ---------------------------------------------------------------------------
// Transpose the V part of qkv (bf16 [T][3072], V at col 2048+h*64+d)
// into vT [H*64][T]  (vT[(h*64+d)*T + t] = V[t][h*64+d]).
// Grid: (T/64, HEADS), block 256 (64x4).
// ---------------------------------------------------------------------------
__global__ __launch_bounds__(256) void transpose_v(
    const bf16* __restrict__ qkvb, bf16* __restrict__ vT) {
  __shared__ bf16 t[64][65];
  const int h = blockIdx.y;
  const int t0 = blockIdx.x * 64;
  const int tx = threadIdx.x & 63, ty = threadIdx.x >> 6;  // ty 0..3
#pragma unroll
  for (int i = 0; i < 16; ++i)
    t[ty + 4 * i][tx] =
        qkvb[(size_t)(t0 + ty + 4 * i) * (3 * EMBED) + 2 * EMBED + h * HDIM + tx];
  __syncthreads();
#pragma unroll
  for (int i = 0; i < 16; ++i)
    vT[((size_t)h * HDIM + ty + 4 * i) * T_SEQ + t0 + tx] = t[tx][ty + 4 * i];
}

// ---------------------------------------------------------------------------
// bf16 MFMA GEMM:  C[M][N] = A[M][K] @ BT[N][K]^T + bias[N]
// 128x128 tile, 256 threads (4 waves, 2x2), BK=32.
// mfma_f32_16x16x32_bf16 fragment layout:
//   A: row = lane&15, k-elems = 8 contiguous at (lane>>4)*8  (same map as B ->
//      any HW k-permutation cancels between operands)
//   D: col = lane&15, row = (lane>>4)*4 + reg   [verified layout]
// ---------------------------------------------------------------------------
template <bool OUT_F32>
__global__ __launch_bounds__(256) void gemm_bt_bias(
    const bf16* __restrict__ A, const bf16* __restrict__ BT,
    const float* __restrict__ bias, void* __restrict__ Cout,
    int M, int N, int K) {
  __shared__ __align__(16) bf16 As[128][40];  // pad 32->40 (stride 80B)
  __shared__ __align__(16) bf16 Bs[128][40];
  const int tid = threadIdx.x;
  const int lane = tid & 63;
  const int w = tid >> 6;
  const int wr = w >> 1, wc = w & 1;
  const int l16 = lane & 15, lq = lane >> 4;
  const int brow = blockIdx.y * 128;
  const int bcol = blockIdx.x * 128;

  f32x4 acc[4][4] = {};

  // staging: 128x32 elems = 4096 bf16; each thread 2 x bf16x8
  const int sr = tid >> 2;           // 0..63
  const int sc = (tid & 3) * 8;      // 0,8,16,24

  bf16x8 ra0, ra1, rb0, rb1;
#define LOAD_REGS(k0)                                                     \
  {                                                                       \
    ra0 = *(const bf16x8*)&A[(size_t)(brow + sr) * K + (k0) + sc];        \
    ra1 = *(const bf16x8*)&A[(size_t)(brow + sr + 64) * K + (k0) + sc];   \
    rb0 = *(const bf16x8*)&BT[(size_t)(bcol + sr) * K + (k0) + sc];       \
    rb1 = *(const bf16x8*)&BT[(size_t)(bcol + sr + 64) * K + (k0) + sc];  \
  }

  LOAD_REGS(0);
  for (int k0 = 0; k0 < K; k0 += 32) {
    __syncthreads();
    *(bf16x8*)&As[sr][sc] = ra0;
    *(bf16x8*)&As[sr + 64][sc] = ra1;
    *(bf16x8*)&Bs[sr][sc] = rb0;
    *(bf16x8*)&Bs[sr + 64][sc] = rb1;
    __syncthreads();
    if (k0 + 32 < K) LOAD_REGS(k0 + 32);

    bf16x8 af[4], bfr[4];
#pragma unroll
    for (int m = 0; m < 4; ++m)
      af[m] = *(const bf16x8*)&As[wr * 64 + m * 16 + l16][lq * 8];
#pragma unroll
    for (int n = 0; n < 4; ++n)
      bfr[n] = *(const bf16x8*)&Bs[wc * 64 + n * 16 + l16][lq * 8];
#pragma unroll
    for (int m = 0; m < 4; ++m)
#pragma unroll
      for (int n = 0; n < 4; ++n)
        acc[m][n] =
            __builtin_amdgcn_mfma_f32_16x16x32_bf16(af[m], bfr[n], acc[m][n], 0, 0, 0);
  }
#undef LOAD_REGS

#pragma unroll
  for (int m = 0; m < 4; ++m) {
    const int row = brow + wr * 64 + m * 16 + lq * 4;
#pragma unroll
    for (int n = 0; n < 4; ++n) {
      const int col = bcol + wc * 64 + n * 16 + l16;
      const float bv = bias[col];
#pragma unroll
      for (int r2 = 0; r2 < 4; ++r2) {
        float v = acc[m][n][r2] + bv;
        if (OUT_F32)
          ((float*)Cout)[(size_t)(row + r2) * N + col] = v;
        else
          ((bf16*)Cout)[(size_t)(row + r2) * N + col] = (bf16)v;
      }
    }
  }
}

// ---------------------------------------------------------------------------
// MFMA causal flash attention (bf16 in/out, fp32 softmax state).
// qkvb: [T][3072] bf16 (q @ h*64+d, k @ 1024+h*64+d)
// vT:   [H*64][T] bf16
// out:  [T][1024] bf16   (out[t][h*64+d])
// Grid (T/64, HEADS), 256 threads = 4 waves; wave w owns q rows w*16..w*16+15.
// ---------------------------------------------------------------------------
__global__ __launch_bounds__(256) void flash_attn_mfma(
    const bf16* __restrict__ qkvb, const bf16* __restrict__ vT,
    bf16* __restrict__ out) {
  const int h = blockIdx.y;
  const int qt = blockIdx.x;
  const int tid = threadIdx.x;
  const int lane = tid & 63;
  const int w = tid >> 6;
  const int l16 = lane & 15, lq = lane >> 4;

  __shared__ __align__(16) bf16 Ks[64][72];      // [key][d]
  __shared__ __align__(16) bf16 Vs[64][72];      // [d][key]  (transposed)
  __shared__ __align__(16) bf16 Ps[4][16][72];   // per-wave P [qrow][k]

  const int qrow_base = qt * 64 + w * 16;

  // Q A-fragments, pre-scaled by 1/sqrt(64)=0.125 (exact in bf16)
  bf16x8 qa[2];
#pragma unroll
  for (int c = 0; c < 2; ++c) {
    bf16x8 v = *(const bf16x8*)&qkvb[(size_t)(qrow_base + l16) * (3 * EMBED) +
                                     h * HDIM + c * 32 + lq * 8];
#pragma unroll
    for (int j = 0; j < 8; ++j) v[j] = (bf16)((float)v[j] * 0.125f);
    qa[c] = v;
  }

  f32x4 acc_o[4] = {};  // [nb]: D[q = lq*4+reg][d = nb*16+l16]
  float m_r[4], l_r[4];
#pragma unroll
  for (int r = 0; r < 4; ++r) { m_r[r] = -INFINITY; l_r[r] = 0.f; }

  const int srr = tid >> 3;           // 0..31
  const int scc = (tid & 7) * 8;      // 0..56

  for (int kt = 0; kt <= qt; ++kt) {
    __syncthreads();  // previous tile's LDS reads done
    // stage K [64key][64d] and V^T [64d][64key]
    *(bf16x8*)&Ks[srr][scc] =
        *(const bf16x8*)&qkvb[(size_t)(kt * 64 + srr) * (3 * EMBED) + EMBED + h * HDIM + scc];
    *(bf16x8*)&Ks[srr + 32][scc] =
        *(const bf16x8*)&qkvb[(size_t)(kt * 64 + srr + 32) * (3 * EMBED) + EMBED + h * HDIM + scc];
    *(bf16x8*)&Vs[srr][scc] =
        *(const bf16x8*)&vT[((size_t)h * HDIM + srr) * T_SEQ + kt * 64 + scc];
    *(bf16x8*)&Vs[srr + 32][scc] =
        *(const bf16x8*)&vT[((size_t)h * HDIM + srr + 32) * T_SEQ + kt * 64 + scc];
    __syncthreads();

    // S = (Q*scale) K^T   -> acc_s[kb]: S[q=lq*4+reg][k=kb*16+l16]
    f32x4 acc_s[4] = {};
#pragma unroll
    for (int kb = 0; kb < 4; ++kb)
#pragma unroll
      for (int c = 0; c < 2; ++c) {
        bf16x8 kf = *(const bf16x8*)&Ks[kb * 16 + l16][c * 32 + lq * 8];
        acc_s[kb] = __builtin_amdgcn_mfma_f32_16x16x32_bf16(qa[c], kf, acc_s[kb], 0, 0, 0);
      }

    // causal mask + online softmax (row stats live in the 16-lane col group)
    // Wave w's q row within the 64-row tile is w*16 + lq*4 + r  (FIX: was
    // missing the w*16 term, which over-masked waves 1..3 on diagonal tiles).
    float sv[4][4];  // [kb][reg]
#pragma unroll
    for (int kb = 0; kb < 4; ++kb)
#pragma unroll
      for (int r = 0; r < 4; ++r) {
        float v = acc_s[kb][r];
        if (kt == qt && (kb * 16 + l16) > (w * 16 + lq * 4 + r)) v = -INFINITY;
        sv[kb][r] = v;
      }

    float corr[4];
#pragma unroll
    for (int r = 0; r < 4; ++r) {
      float v = fmaxf(fmaxf(sv[0][r], sv[1][r]), fmaxf(sv[2][r], sv[3][r]));
      v = fmaxf(v, __shfl_xor(v, 1));
      v = fmaxf(v, __shfl_xor(v, 2));
      v = fmaxf(v, __shfl_xor(v, 4));
      v = fmaxf(v, __shfl_xor(v, 8));
      const float mnew = fmaxf(m_r[r], v);
      corr[r] = __expf(m_r[r] - mnew);
      m_r[r] = mnew;
    }

    float lt[4] = {0.f, 0.f, 0.f, 0.f};
#pragma unroll
    for (int kb = 0; kb < 4; ++kb)
#pragma unroll
      for (int r = 0; r < 4; ++r) {
        const float p = __expf(sv[kb][r] - m_r[r]);
        sv[kb][r] = p;
        lt[r] += p;
      }
#pragma unroll
    for (int r = 0; r < 4; ++r) {
      float s = lt[r];
      s += __shfl_xor(s, 1);
      s += __shfl_xor(s, 2);
      s += __shfl_xor(s, 4);
      s += __shfl_xor(s, 8);
      l_r[r] = l_r[r] * corr[r] + s;
    }

    // rescale O
#pragma unroll
    for (int nb = 0; nb < 4; ++nb)
#pragma unroll
      for (int r = 0; r < 4; ++r) acc_o[nb][r] *= corr[r];

    // P -> wave-private LDS (same-wave DS ordering; no barrier needed)
#pragma unroll
    for (int kb = 0; kb < 4; ++kb)
#pragma unroll
      for (int r = 0; r < 4; ++r)
        Ps[w][lq * 4 + r][kb * 16 + l16] = (bf16)sv[kb][r];

    bf16x8 pa[2];
#pragma unroll
    for (int c = 0; c < 2; ++c)
      pa[c] = *(const bf16x8*)&Ps[w][l16][c * 32 + lq * 8];

    // O += P V : B-frag of V from Vs[d][key]
#pragma unroll
    for (int nb = 0; nb < 4; ++nb)
#pragma unroll
      for (int c = 0; c < 2; ++c) {
        bf16x8 vf = *(const bf16x8*)&Vs[nb * 16 + l16][c * 32 + lq * 8];
        acc_o[nb] = __builtin_amdgcn_mfma_f32_16x16x32_bf16(pa[c], vf, acc_o[nb], 0, 0, 0);
      }
  }

  float inv[4];
#pragma unroll
  for (int r = 0; r < 4; ++r) inv[r] = 1.f / l_r[r];
#pragma unroll
  for (int nb = 0; nb < 4; ++nb)
#pragma unroll
    for (int r = 0; r < 4; ++r)
      out[(size_t)(qrow_base + lq * 4 + r) * EMBED + h * HDIM + nb * 16 + l16] =
          (bf16)(acc_o[nb][r] * inv[r]);
}

// ---------------------------------------------------------------------------
extern "C" void kernel_launch(void* const* d_in, const int* in_sizes, int n_in,
                              void* d_out, int out_size, void* d_ws, size_t ws_size,
                              hipStream_t stream) {
  const float* x     = (const float*)d_in[0];   // [1,4096,1024]
  const float* W_qkv = (const float*)d_in[1];   // [1024,3072]
  const float* b_qkv = (const float*)d_in[2];   // [3072]
  const float* W_out = (const float*)d_in[3];   // [1024,1024]
  const float* b_out = (const float*)d_in[4];   // [1024]
  float* out = (float*)d_out;                   // [1,4096,1024] fp32

  char* ws = (char*)d_ws;
  const size_t MB = 1024 * 1024;
  bf16* x_bf   = (bf16*)(ws + 0);        // 8 MB  [4096][1024]
  bf16* WqkvT  = (bf16*)(ws + 8 * MB);   // 6 MB  [3072][1024]
  bf16* WoutT  = (bf16*)(ws + 14 * MB);  // 2 MB  [1024][1024]
  bf16* qkvb   = (bf16*)(ws + 16 * MB);  // 24 MB [4096][3072]
  bf16* vT     = (bf16*)(ws + 40 * MB);  // 8 MB  [1024][4096]
  bf16* attn_o = (bf16*)(ws + 48 * MB);  // 8 MB  [4096][1024]

  // convert / transpose inputs to bf16
  f32_to_bf16<<<(T_SEQ * EMBED) / (256 * 8), 256, 0, stream>>>(x, x_bf, T_SEQ * EMBED);
  transpose_f32_bf16<<<dim3(3 * EMBED / 32, EMBED / 32), 256, 0, stream>>>(
      W_qkv, WqkvT, EMBED, 3 * EMBED);
  transpose_f32_bf16<<<dim3(EMBED / 32, EMBED / 32), 256, 0, stream>>>(
      W_out, WoutT, EMBED, EMBED);

  // QKV projection: [4096,1024] @ [1024,3072] + b -> bf16
  gemm_bt_bias<false><<<dim3(3 * EMBED / 128, T_SEQ / 128), 256, 0, stream>>>(
      x_bf, WqkvT, b_qkv, qkvb, T_SEQ, 3 * EMBED, EMBED);

  // V -> V^T
  transpose_v<<<dim3(T_SEQ / 64, HEADS), 256, 0, stream>>>(qkvb, vT);

  // causal flash attention
  flash_attn_mfma<<<dim3(T_SEQ / 64, HEADS), 256, 0, stream>>>(qkvb, vT, attn_o);

  // output projection: [4096,1024] @ [1024,1024] + b -> fp32
  gemm_bt_bias<true><<<dim3(EMBED / 128, T_SEQ / 128), 256, 0, stream>>>(
      attn_o, WoutT, b_out, out, T_SEQ, EMBED, EMBED);
}

// Round 4
// 183.310 us; speedup vs baseline: 23.5771x; 1.6218x over previous
//
#include <hip/hip_runtime.h>
#include <hip/hip_bf16.h>
#include <math.h>

#define EMBED 1024
#define HEADS 16
#define HDIM 64
#define T_SEQ 4096

typedef __bf16 bf16;
typedef bf16 bf16x8 __attribute__((ext_vector_type(8)));
typedef float f32x4 __attribute__((ext_vector_type(4)));
typedef float f32x16 __attribute__((ext_vector_type(16)));

// ---------------------------------------------------------------------------
// fp32 -> bf16 elementwise (n % 8 == 0)
// ---------------------------------------------------------------------------
__global__ __launch_bounds__(256) void f32_to_bf16(
    const float* __restrict__ in, bf16* __restrict__ out, int n) {
  int i = (blockIdx.x * 256 + threadIdx.x) * 8;
  if (i >= n) return;
  float4 a = *(const float4*)&in[i];
  float4 b = *(const float4*)&in[i + 4];
  bf16x8 o;
  o[0] = (bf16)a.x; o[1] = (bf16)a.y; o[2] = (bf16)a.z; o[3] = (bf16)a.w;
  o[4] = (bf16)b.x; o[5] = (bf16)b.y; o[6] = (bf16)b.z; o[7] = (bf16)b.w;
  *(bf16x8*)&out[i] = o;
}

// ---------------------------------------------------------------------------
// Transpose fp32 [rows][cols] -> bf16 [cols][rows].  rows%32==0, cols%32==0.
// ---------------------------------------------------------------------------
__global__ __launch_bounds__(256) void transpose_f32_bf16(
    const float* __restrict__ in, bf16* __restrict__ out, int rows, int cols) {
  __shared__ bf16 t[32][33];
  const int c0 = blockIdx.x * 32, r0 = blockIdx.y * 32;
  const int tx = threadIdx.x & 31, ty = threadIdx.x >> 5;  // ty 0..7
#pragma unroll
  for (int i = 0; i < 4; ++i)
    t[ty + 8 * i][tx] = (bf16)in[(size_t)(r0 + ty + 8 * i) * cols + c0 + tx];
  __syncthreads();
#pragma unroll
  for (int i = 0; i < 4; ++i)
    out[(size_t)(c0 + ty + 8 * i) * rows + r0 + tx] = t[tx][ty + 8 * i];
}

// ---------------------------------------------------------------------------
// Transpose V part of qkv (bf16 [T][3072], V at col 2048+h*64+d)
// into vT [H*64][T].
// ---------------------------------------------------------------------------
__global__ __launch_bounds__(256) void transpose_v(
    const bf16* __restrict__ qkvb, bf16* __restrict__ vT) {
  __shared__ bf16 t[64][65];
  const int h = blockIdx.y;
  const int t0 = blockIdx.x * 64;
  const int tx = threadIdx.x & 63, ty = threadIdx.x >> 6;  // ty 0..3
#pragma unroll
  for (int i = 0; i < 16; ++i)
    t[ty + 4 * i][tx] =
        qkvb[(size_t)(t0 + ty + 4 * i) * (3 * EMBED) + 2 * EMBED + h * HDIM + tx];
  __syncthreads();
#pragma unroll
  for (int i = 0; i < 16; ++i)
    vT[((size_t)h * HDIM + ty + 4 * i) * T_SEQ + t0 + tx] = t[tx][ty + 4 * i];
}

// ---------------------------------------------------------------------------
// bf16 MFMA GEMM:  C[M][N] = A[M][K] @ BT[N][K]^T + bias[N]   (unchanged)
// ---------------------------------------------------------------------------
template <bool OUT_F32>
__global__ __launch_bounds__(256) void gemm_bt_bias(
    const bf16* __restrict__ A, const bf16* __restrict__ BT,
    const float* __restrict__ bias, void* __restrict__ Cout,
    int M, int N, int K) {
  __shared__ __align__(16) bf16 As[128][40];
  __shared__ __align__(16) bf16 Bs[128][40];
  const int tid = threadIdx.x;
  const int lane = tid & 63;
  const int w = tid >> 6;
  const int wr = w >> 1, wc = w & 1;
  const int l16 = lane & 15, lq = lane >> 4;
  const int brow = blockIdx.y * 128;
  const int bcol = blockIdx.x * 128;

  f32x4 acc[4][4] = {};

  const int sr = tid >> 2;
  const int sc = (tid & 3) * 8;

  bf16x8 ra0, ra1, rb0, rb1;
#define LOAD_REGS(k0)                                                     \
  {                                                                       \
    ra0 = *(const bf16x8*)&A[(size_t)(brow + sr) * K + (k0) + sc];        \
    ra1 = *(const bf16x8*)&A[(size_t)(brow + sr + 64) * K + (k0) + sc];   \
    rb0 = *(const bf16x8*)&BT[(size_t)(bcol + sr) * K + (k0) + sc];       \
    rb1 = *(const bf16x8*)&BT[(size_t)(bcol + sr + 64) * K + (k0) + sc];  \
  }

  LOAD_REGS(0);
  for (int k0 = 0; k0 < K; k0 += 32) {
    __syncthreads();
    *(bf16x8*)&As[sr][sc] = ra0;
    *(bf16x8*)&As[sr + 64][sc] = ra1;
    *(bf16x8*)&Bs[sr][sc] = rb0;
    *(bf16x8*)&Bs[sr + 64][sc] = rb1;
    __syncthreads();
    if (k0 + 32 < K) LOAD_REGS(k0 + 32);

    bf16x8 af[4], bfr[4];
#pragma unroll
    for (int m = 0; m < 4; ++m)
      af[m] = *(const bf16x8*)&As[wr * 64 + m * 16 + l16][lq * 8];
#pragma unroll
    for (int n = 0; n < 4; ++n)
      bfr[n] = *(const bf16x8*)&Bs[wc * 64 + n * 16 + l16][lq * 8];
#pragma unroll
    for (int m = 0; m < 4; ++m)
#pragma unroll
      for (int n = 0; n < 4; ++n)
        acc[m][n] =
            __builtin_amdgcn_mfma_f32_16x16x32_bf16(af[m], bfr[n], acc[m][n], 0, 0, 0);
  }
#undef LOAD_REGS

#pragma unroll
  for (int m = 0; m < 4; ++m) {
    const int row = brow + wr * 64 + m * 16 + lq * 4;
#pragma unroll
    for (int n = 0; n < 4; ++n) {
      const int col = bcol + wc * 64 + n * 16 + l16;
      const float bv = bias[col];
#pragma unroll
      for (int r2 = 0; r2 < 4; ++r2) {
        float v = acc[m][n][r2] + bv;
        if (OUT_F32)
          ((float*)Cout)[(size_t)(row + r2) * N + col] = v;
        else
          ((bf16*)Cout)[(size_t)(row + r2) * N + col] = (bf16)v;
      }
    }
  }
}

// ---------------------------------------------------------------------------
// cvt_pk + permlane32_swap: from 8 per-lane floats (the (reg&3)+8*(reg>>2)+4*hi
// layout of a 32x32 D-fragment quad-pair) build one 8-elem bf16 A/B-fragment
// (k = hi*8 + j contiguous). Lanes<32 get elems 0..7, lanes>=32 get 8..15.
// ---------------------------------------------------------------------------
__device__ __forceinline__ bf16x8 pk_swap8(float a0, float a1, float a2, float a3,
                                           float a4, float a5, float a6, float a7) {
  unsigned W0, W1, W2, W3;
  asm("v_cvt_pk_bf16_f32 %0, %1, %2" : "=v"(W0) : "v"(a0), "v"(a1));
  asm("v_cvt_pk_bf16_f32 %0, %1, %2" : "=v"(W1) : "v"(a2), "v"(a3));
  asm("v_cvt_pk_bf16_f32 %0, %1, %2" : "=v"(W2) : "v"(a4), "v"(a5));
  asm("v_cvt_pk_bf16_f32 %0, %1, %2" : "=v"(W3) : "v"(a6), "v"(a7));
  asm("v_permlane32_swap_b32 %0, %1" : "+v"(W0), "+v"(W2));
  asm("v_permlane32_swap_b32 %0, %1" : "+v"(W1), "+v"(W3));
  union { unsigned u[4]; bf16x8 v; } r;
  r.u[0] = W0; r.u[1] = W1; r.u[2] = W2; r.u[3] = W3;
  return r.v;
}

// ---------------------------------------------------------------------------
// Swapped-layout MFMA flash attention (m214/HK structure).
// qkvb: [T][3072] bf16; vT: [H*64][T] bf16; out: [T][1024] bf16.
// Grid (T/128, HEADS) with x REVERSED (big qt first); 256 thr = 4 waves;
// wave w owns q rows qtb*128 + w*32 .. +31, one q per lane pair (q = lane&31).
// S^T = mfma(K, Q): lane holds 32 S vals for its q. Softmax lane-local.
// O^T = mfma(V^T, P^T): O also q-per-lane -> corr rescale is plain muls.
// K/V LDS tiles XOR-swizzled (16B slot ^= row&7): conflict-free b128.
// ---------------------------------------------------------------------------
__global__ __launch_bounds__(256) void flash_attn_mfma(
    const bf16* __restrict__ qkvb, const bf16* __restrict__ vT,
    bf16* __restrict__ out) {
  const int h = blockIdx.y;
  const int qtb = (int)gridDim.x - 1 - (int)blockIdx.x;  // reversed: big first
  const int q0 = qtb * 128;
  const int tid = threadIdx.x;
  const int lane = tid & 63;
  const int w = tid >> 6;
  const int qi = lane & 31;   // q index within wave tile
  const int hi = lane >> 5;   // k-half selector

  __shared__ __align__(16) bf16 Ks[64 * 64];  // [key][d], swizzled
  __shared__ __align__(16) bf16 Vs[64 * 64];  // [d][key], swizzled

  const int qrow = q0 + w * 32 + qi;

  // Q B-fragments (col=q=lane&31, k=d chunk c: d = c*16 + hi*8 + j), x0.125
  bf16x8 qb0, qb1, qb2, qb3;
  {
    const bf16* qp = &qkvb[(size_t)qrow * (3 * EMBED) + h * HDIM + hi * 8];
    qb0 = *(const bf16x8*)(qp + 0);
    qb1 = *(const bf16x8*)(qp + 16);
    qb2 = *(const bf16x8*)(qp + 32);
    qb3 = *(const bf16x8*)(qp + 48);
#pragma unroll
    for (int j = 0; j < 8; ++j) {
      qb0[j] = (bf16)((float)qb0[j] * 0.125f);
      qb1[j] = (bf16)((float)qb1[j] * 0.125f);
      qb2[j] = (bf16)((float)qb2[j] * 0.125f);
      qb3[j] = (bf16)((float)qb3[j] * 0.125f);
    }
  }

  f32x16 oA = {}, oB = {};        // O^T: d 0-31 / 32-63 rows, q = lane&31 col
  float m_r = -INFINITY, l_r = 0.f;

  // staging roles: row r = tid>>3 (+32), 16B slot s = tid&7
  const int strow = tid >> 3;
  const int stslot = tid & 7;
  const int nt = 2 * qtb + 2;

  bf16x8 rk0, rk1, rv0, rv1;
#define LOAD_KV(kt)                                                                \
  {                                                                                \
    rk0 = *(const bf16x8*)&qkvb[(size_t)((kt) * 64 + strow) * (3 * EMBED) + EMBED + \
                                h * HDIM + stslot * 8];                            \
    rk1 = *(const bf16x8*)&qkvb[(size_t)((kt) * 64 + strow + 32) * (3 * EMBED) +   \
                                EMBED + h * HDIM + stslot * 8];                    \
    rv0 = *(const bf16x8*)&vT[((size_t)h * HDIM + strow) * T_SEQ + (kt) * 64 +     \
                              stslot * 8];                                         \
    rv1 = *(const bf16x8*)&vT[((size_t)h * HDIM + strow + 32) * T_SEQ + (kt) * 64 + \
                              stslot * 8];                                         \
  }

  LOAD_KV(0);
  for (int kt = 0; kt < nt; ++kt) {
    __syncthreads();  // previous tile's LDS reads done
    *(bf16x8*)&Ks[strow * 64 + ((stslot ^ (strow & 7)) << 3)] = rk0;
    *(bf16x8*)&Ks[(strow + 32) * 64 + ((stslot ^ (strow & 7)) << 3)] = rk1;
    *(bf16x8*)&Vs[strow * 64 + ((stslot ^ (strow & 7)) << 3)] = rv0;
    *(bf16x8*)&Vs[(strow + 32) * 64 + ((stslot ^ (strow & 7)) << 3)] = rv1;
    __syncthreads();  // LDS ready
    if (kt + 1 < nt) LOAD_KV(kt + 1);  // issue next-tile loads; land during compute

    // fully-masked tile for this wave? (min key > max q) -> skip compute
    if (kt * 64 > q0 + w * 32 + 31) continue;

    // ---- S^T = mfma(K, Q): accA keys 0-31, accB keys 32-63 ----
    f32x16 sA = {}, sB = {};
    __builtin_amdgcn_s_setprio(1);
#pragma unroll
    for (int c = 0; c < 4; ++c) {
      const int sl = ((2 * c + hi) ^ (qi & 7)) << 3;
      bf16x8 kfA = *(const bf16x8*)&Ks[qi * 64 + sl];
      bf16x8 kfB = *(const bf16x8*)&Ks[(qi + 32) * 64 + sl];
      bf16x8 qf = (c == 0) ? qb0 : (c == 1) ? qb1 : (c == 2) ? qb2 : qb3;
      sA = __builtin_amdgcn_mfma_f32_32x32x16_bf16(kfA, qf, sA, 0, 0, 0);
      sB = __builtin_amdgcn_mfma_f32_32x32x16_bf16(kfB, qf, sB, 0, 0, 0);
    }
    __builtin_amdgcn_s_setprio(0);

    // ---- causal mask (element key_g > q_g) ----
    if (kt * 64 + 63 > q0 + w * 32) {
      const int qg = qrow;
#pragma unroll
      for (int r = 0; r < 16; ++r) {
        const int kl = (r & 3) + 8 * (r >> 2) + 4 * hi;
        if (kt * 64 + kl > qg) sA[r] = -INFINITY;
        if (kt * 64 + 32 + kl > qg) sB[r] = -INFINITY;
      }
    }

    // ---- online softmax (lane-local + one xor32) ----
    float pm = sA[0];
#pragma unroll
    for (int r = 1; r < 16; ++r) pm = fmaxf(pm, sA[r]);
#pragma unroll
    for (int r = 0; r < 16; ++r) pm = fmaxf(pm, sB[r]);
    pm = fmaxf(pm, __shfl_xor(pm, 32));
    const float mnew = fmaxf(m_r, pm);
    const float corr = __expf(m_r - mnew);
    m_r = mnew;

    float ls = 0.f;
#pragma unroll
    for (int r = 0; r < 16; ++r) {
      sA[r] = __expf(sA[r] - mnew);
      ls += sA[r];
    }
#pragma unroll
    for (int r = 0; r < 16; ++r) {
      sB[r] = __expf(sB[r] - mnew);
      ls += sB[r];
    }
    l_r = l_r * corr + ls;

#pragma unroll
    for (int r = 0; r < 16; ++r) { oA[r] *= corr; oB[r] *= corr; }

    // ---- P^T B-fragments (keys chunks 0..3) ----
    bf16x8 pf0 = pk_swap8(sA[0], sA[1], sA[2], sA[3], sA[4], sA[5], sA[6], sA[7]);
    bf16x8 pf1 = pk_swap8(sA[8], sA[9], sA[10], sA[11], sA[12], sA[13], sA[14], sA[15]);
    bf16x8 pf2 = pk_swap8(sB[0], sB[1], sB[2], sB[3], sB[4], sB[5], sB[6], sB[7]);
    bf16x8 pf3 = pk_swap8(sB[8], sB[9], sB[10], sB[11], sB[12], sB[13], sB[14], sB[15]);

    // ---- O^T += mfma(V^T, P^T) ----
    __builtin_amdgcn_s_setprio(1);
#pragma unroll
    for (int c = 0; c < 4; ++c) {
      const int sl = ((2 * c + hi) ^ (qi & 7)) << 3;
      bf16x8 vfA = *(const bf16x8*)&Vs[qi * 64 + sl];
      bf16x8 vfB = *(const bf16x8*)&Vs[(qi + 32) * 64 + sl];
      bf16x8 pf = (c == 0) ? pf0 : (c == 1) ? pf1 : (c == 2) ? pf2 : pf3;
      oA = __builtin_amdgcn_mfma_f32_32x32x16_bf16(vfA, pf, oA, 0, 0, 0);
      oB = __builtin_amdgcn_mfma_f32_32x32x16_bf16(vfB, pf, oB, 0, 0, 0);
    }
    __builtin_amdgcn_s_setprio(0);
  }
#undef LOAD_KV

  // ---- epilogue: O^T / l, pk+swap into coalesced 16B stores ----
  const float lt = l_r + __shfl_xor(l_r, 32);
  const float inv = 1.f / lt;
#pragma unroll
  for (int r = 0; r < 16; ++r) { oA[r] *= inv; oB[r] *= inv; }

  bf16* ob = &out[(size_t)qrow * EMBED + h * HDIM];
  // d 0-15 (lanes<32: d0-7 | lanes>=32: d8-15), d 16-31, d 32-47, d 48-63
  *(bf16x8*)(ob + hi * 8) =
      pk_swap8(oA[0], oA[1], oA[2], oA[3], oA[4], oA[5], oA[6], oA[7]);
  *(bf16x8*)(ob + 16 + hi * 8) =
      pk_swap8(oA[8], oA[9], oA[10], oA[11], oA[12], oA[13], oA[14], oA[15]);
  *(bf16x8*)(ob + 32 + hi * 8) =
      pk_swap8(oB[0], oB[1], oB[2], oB[3], oB[4], oB[5], oB[6], oB[7]);
  *(bf16x8*)(ob + 48 + hi * 8) =
      pk_swap8(oB[8], oB[9], oB[10], oB[11], oB[12], oB[13], oB[14], oB[15]);
}

// ---------------------------------------------------------------------------
extern "C" void kernel_launch(void* const* d_in, const int* in_sizes, int n_in,
                              void* d_out, int out_size, void* d_ws, size_t ws_size,
                              hipStream_t stream) {
  const float* x     = (const float*)d_in[0];   // [1,4096,1024]
  const float* W_qkv = (const float*)d_in[1];   // [1024,3072]
  const float* b_qkv = (const float*)d_in[2];   // [3072]
  const float* W_out = (const float*)d_in[3];   // [1024,1024]
  const float* b_out = (const float*)d_in[4];   // [1024]
  float* out = (float*)d_out;                   // [1,4096,1024] fp32

  char* ws = (char*)d_ws;
  const size_t MB = 1024 * 1024;
  bf16* x_bf   = (bf16*)(ws + 0);        // 8 MB  [4096][1024]
  bf16* WqkvT  = (bf16*)(ws + 8 * MB);   // 6 MB  [3072][1024]
  bf16* WoutT  = (bf16*)(ws + 14 * MB);  // 2 MB  [1024][1024]
  bf16* qkvb   = (bf16*)(ws + 16 * MB);  // 24 MB [4096][3072]
  bf16* vT     = (bf16*)(ws + 40 * MB);  // 8 MB  [1024][4096]
  bf16* attn_o = (bf16*)(ws + 48 * MB);  // 8 MB  [4096][1024]

  f32_to_bf16<<<(T_SEQ * EMBED) / (256 * 8), 256, 0, stream>>>(x, x_bf, T_SEQ * EMBED);
  transpose_f32_bf16<<<dim3(3 * EMBED / 32, EMBED / 32), 256, 0, stream>>>(
      W_qkv, WqkvT, EMBED, 3 * EMBED);
  transpose_f32_bf16<<<dim3(EMBED / 32, EMBED / 32), 256, 0, stream>>>(
      W_out, WoutT, EMBED, EMBED);

  gemm_bt_bias<false><<<dim3(3 * EMBED / 128, T_SEQ / 128), 256, 0, stream>>>(
      x_bf, WqkvT, b_qkv, qkvb, T_SEQ, 3 * EMBED, EMBED);

  transpose_v<<<dim3(T_SEQ / 64, HEADS), 256, 0, stream>>>(qkvb, vT);

  flash_attn_mfma<<<dim3(T_SEQ / 128, HEADS), 256, 0, stream>>>(qkvb, vT, attn_o);

  gemm_bt_bias<true><<<dim3(EMBED / 128, T_SEQ / 128), 256, 0, stream>>>(
      attn_o, WoutT, b_out, out, T_SEQ, EMBED, EMBED);
}

// Round 5
// 175.125 us; speedup vs baseline: 24.6791x; 1.0467x over previous
//
#include <hip/hip_runtime.h>
#include <hip/hip_bf16.h>
#include <math.h>

#define EMBED 1024
#define HEADS 16
#define HDIM 64
#define T_SEQ 4096

typedef __bf16 bf16;
typedef bf16 bf16x8 __attribute__((ext_vector_type(8)));
typedef float f32x4 __attribute__((ext_vector_type(4)));
typedef float f32x16 __attribute__((ext_vector_type(16)));

// ---------------------------------------------------------------------------
// fp32 -> bf16 elementwise (n % 8 == 0)
// ---------------------------------------------------------------------------
__global__ __launch_bounds__(256) void f32_to_bf16(
    const float* __restrict__ in, bf16* __restrict__ out, int n) {
  int i = (blockIdx.x * 256 + threadIdx.x) * 8;
  if (i >= n) return;
  float4 a = *(const float4*)&in[i];
  float4 b = *(const float4*)&in[i + 4];
  bf16x8 o;
  o[0] = (bf16)a.x; o[1] = (bf16)a.y; o[2] = (bf16)a.z; o[3] = (bf16)a.w;
  o[4] = (bf16)b.x; o[5] = (bf16)b.y; o[6] = (bf16)b.z; o[7] = (bf16)b.w;
  *(bf16x8*)&out[i] = o;
}

// ---------------------------------------------------------------------------
// Transpose fp32 [rows][cols] -> bf16 [cols][rows].
// ---------------------------------------------------------------------------
__global__ __launch_bounds__(256) void transpose_f32_bf16(
    const float* __restrict__ in, bf16* __restrict__ out, int rows, int cols) {
  __shared__ bf16 t[32][33];
  const int c0 = blockIdx.x * 32, r0 = blockIdx.y * 32;
  const int tx = threadIdx.x & 31, ty = threadIdx.x >> 5;
#pragma unroll
  for (int i = 0; i < 4; ++i)
    t[ty + 8 * i][tx] = (bf16)in[(size_t)(r0 + ty + 8 * i) * cols + c0 + tx];
  __syncthreads();
#pragma unroll
  for (int i = 0; i < 4; ++i)
    out[(size_t)(c0 + ty + 8 * i) * rows + r0 + tx] = t[tx][ty + 8 * i];
}

// ---------------------------------------------------------------------------
// Transpose V part of qkv into vT [H*64][T].
// ---------------------------------------------------------------------------
__global__ __launch_bounds__(256) void transpose_v(
    const bf16* __restrict__ qkvb, bf16* __restrict__ vT) {
  __shared__ bf16 t[64][65];
  const int h = blockIdx.y;
  const int t0 = blockIdx.x * 64;
  const int tx = threadIdx.x & 63, ty = threadIdx.x >> 6;
#pragma unroll
  for (int i = 0; i < 16; ++i)
    t[ty + 4 * i][tx] =
        qkvb[(size_t)(t0 + ty + 4 * i) * (3 * EMBED) + 2 * EMBED + h * HDIM + tx];
  __syncthreads();
#pragma unroll
  for (int i = 0; i < 16; ++i)
    vT[((size_t)h * HDIM + ty + 4 * i) * T_SEQ + t0 + tx] = t[tx][ty + 4 * i];
}

// ---------------------------------------------------------------------------
// bf16 MFMA GEMM:  C[M][N] = A[M][K] @ BT[N][K]^T + bias[N]   (unchanged)
// ---------------------------------------------------------------------------
template <bool OUT_F32>
__global__ __launch_bounds__(256) void gemm_bt_bias(
    const bf16* __restrict__ A, const bf16* __restrict__ BT,
    const float* __restrict__ bias, void* __restrict__ Cout,
    int M, int N, int K) {
  __shared__ __align__(16) bf16 As[128][40];
  __shared__ __align__(16) bf16 Bs[128][40];
  const int tid = threadIdx.x;
  const int lane = tid & 63;
  const int w = tid >> 6;
  const int wr = w >> 1, wc = w & 1;
  const int l16 = lane & 15, lq = lane >> 4;
  const int brow = blockIdx.y * 128;
  const int bcol = blockIdx.x * 128;

  f32x4 acc[4][4] = {};

  const int sr = tid >> 2;
  const int sc = (tid & 3) * 8;

  bf16x8 ra0, ra1, rb0, rb1;
#define LOAD_REGS(k0)                                                     \
  {                                                                       \
    ra0 = *(const bf16x8*)&A[(size_t)(brow + sr) * K + (k0) + sc];        \
    ra1 = *(const bf16x8*)&A[(size_t)(brow + sr + 64) * K + (k0) + sc];   \
    rb0 = *(const bf16x8*)&BT[(size_t)(bcol + sr) * K + (k0) + sc];       \
    rb1 = *(const bf16x8*)&BT[(size_t)(bcol + sr + 64) * K + (k0) + sc];  \
  }

  LOAD_REGS(0);
  for (int k0 = 0; k0 < K; k0 += 32) {
    __syncthreads();
    *(bf16x8*)&As[sr][sc] = ra0;
    *(bf16x8*)&As[sr + 64][sc] = ra1;
    *(bf16x8*)&Bs[sr][sc] = rb0;
    *(bf16x8*)&Bs[sr + 64][sc] = rb1;
    __syncthreads();
    if (k0 + 32 < K) LOAD_REGS(k0 + 32);

    bf16x8 af[4], bfr[4];
#pragma unroll
    for (int m = 0; m < 4; ++m)
      af[m] = *(const bf16x8*)&As[wr * 64 + m * 16 + l16][lq * 8];
#pragma unroll
    for (int n = 0; n < 4; ++n)
      bfr[n] = *(const bf16x8*)&Bs[wc * 64 + n * 16 + l16][lq * 8];
#pragma unroll
    for (int m = 0; m < 4; ++m)
#pragma unroll
      for (int n = 0; n < 4; ++n)
        acc[m][n] =
            __builtin_amdgcn_mfma_f32_16x16x32_bf16(af[m], bfr[n], acc[m][n], 0, 0, 0);
  }
#undef LOAD_REGS

#pragma unroll
  for (int m = 0; m < 4; ++m) {
    const int row = brow + wr * 64 + m * 16 + lq * 4;
#pragma unroll
    for (int n = 0; n < 4; ++n) {
      const int col = bcol + wc * 64 + n * 16 + l16;
      const float bv = bias[col];
#pragma unroll
      for (int r2 = 0; r2 < 4; ++r2) {
        float v = acc[m][n][r2] + bv;
        if (OUT_F32)
          ((float*)Cout)[(size_t)(row + r2) * N + col] = v;
        else
          ((bf16*)Cout)[(size_t)(row + r2) * N + col] = (bf16)v;
      }
    }
  }
}

// ---------------------------------------------------------------------------
// cvt_pk + permlane32_swap packing helper (see round 4).
// ---------------------------------------------------------------------------
__device__ __forceinline__ bf16x8 pk_swap8(float a0, float a1, float a2, float a3,
                                           float a4, float a5, float a6, float a7) {
  unsigned W0, W1, W2, W3;
  asm("v_cvt_pk_bf16_f32 %0, %1, %2" : "=v"(W0) : "v"(a0), "v"(a1));
  asm("v_cvt_pk_bf16_f32 %0, %1, %2" : "=v"(W1) : "v"(a2), "v"(a3));
  asm("v_cvt_pk_bf16_f32 %0, %1, %2" : "=v"(W2) : "v"(a4), "v"(a5));
  asm("v_cvt_pk_bf16_f32 %0, %1, %2" : "=v"(W3) : "v"(a6), "v"(a7));
  asm("v_permlane32_swap_b32 %0, %1" : "+v"(W0), "+v"(W2));
  asm("v_permlane32_swap_b32 %0, %1" : "+v"(W1), "+v"(W3));
  union { unsigned u[4]; bf16x8 v; } r;
  r.u[0] = W0; r.u[1] = W1; r.u[2] = W2; r.u[3] = W3;
  return r.v;
}

// ---------------------------------------------------------------------------
// Swapped-layout MFMA flash attention with KV-split (flash-decoding style).
// Grid x in [0,48), reversed (big jobs first):
//   x<32, qtb=x<16  : full kv range [0, 2qtb+2), write out directly
//   x<32, qtb=x>=16 : part 0, kv [0, qtb+1), write partial slot 0
//   x>=32, qtb=x-16 : part 1, kv [qtb+1, 2qtb+2), write partial slot 1
// Partials: normalized O (bf16) + (m,l) per row; merged by merge_partials.
// ---------------------------------------------------------------------------
__global__ __launch_bounds__(256) void flash_attn_mfma(
    const bf16* __restrict__ qkvb, const bf16* __restrict__ vT,
    bf16* __restrict__ out, bf16* __restrict__ partO,
    float2* __restrict__ partML) {
  const int h = blockIdx.y;
  const int x = 47 - (int)blockIdx.x;  // reversed: big first
  int qtb, k0t, k1t, slot;
  if (x < 32) {
    qtb = x;
    k0t = 0;
    if (qtb < 16) { k1t = 2 * qtb + 2; slot = -1; }
    else          { k1t = qtb + 1;     slot = 0;  }
  } else {
    qtb = x - 16;
    k0t = qtb + 1;
    k1t = 2 * qtb + 2;
    slot = 1;
  }
  const int q0 = qtb * 128;
  const int tid = threadIdx.x;
  const int lane = tid & 63;
  const int w = tid >> 6;
  const int qi = lane & 31;   // q index within wave tile
  const int hi = lane >> 5;   // k-half selector

  __shared__ __align__(16) bf16 Ks[64 * 64];  // [key][d], swizzled
  __shared__ __align__(16) bf16 Vs[64 * 64];  // [d][key], swizzled

  const int qrow = q0 + w * 32 + qi;

  // Q B-fragments, pre-scaled by 0.125
  bf16x8 qb0, qb1, qb2, qb3;
  {
    const bf16* qp = &qkvb[(size_t)qrow * (3 * EMBED) + h * HDIM + hi * 8];
    qb0 = *(const bf16x8*)(qp + 0);
    qb1 = *(const bf16x8*)(qp + 16);
    qb2 = *(const bf16x8*)(qp + 32);
    qb3 = *(const bf16x8*)(qp + 48);
#pragma unroll
    for (int j = 0; j < 8; ++j) {
      qb0[j] = (bf16)((float)qb0[j] * 0.125f);
      qb1[j] = (bf16)((float)qb1[j] * 0.125f);
      qb2[j] = (bf16)((float)qb2[j] * 0.125f);
      qb3[j] = (bf16)((float)qb3[j] * 0.125f);
    }
  }

  f32x16 oA = {}, oB = {};
  float m_r = -INFINITY, l_r = 0.f;

  const int strow = tid >> 3;
  const int stslot = tid & 7;

  bf16x8 rk0, rk1, rv0, rv1;
#define LOAD_KV(kt)                                                                 \
  {                                                                                 \
    rk0 = *(const bf16x8*)&qkvb[(size_t)((kt) * 64 + strow) * (3 * EMBED) + EMBED + \
                                h * HDIM + stslot * 8];                             \
    rk1 = *(const bf16x8*)&qkvb[(size_t)((kt) * 64 + strow + 32) * (3 * EMBED) +    \
                                EMBED + h * HDIM + stslot * 8];                     \
    rv0 = *(const bf16x8*)&vT[((size_t)h * HDIM + strow) * T_SEQ + (kt) * 64 +      \
                              stslot * 8];                                          \
    rv1 = *(const bf16x8*)&vT[((size_t)h * HDIM + strow + 32) * T_SEQ + (kt) * 64 + \
                              stslot * 8];                                          \
  }

  LOAD_KV(k0t);
  for (int kt = k0t; kt < k1t; ++kt) {
    __syncthreads();
    *(bf16x8*)&Ks[strow * 64 + ((stslot ^ (strow & 7)) << 3)] = rk0;
    *(bf16x8*)&Ks[(strow + 32) * 64 + ((stslot ^ (strow & 7)) << 3)] = rk1;
    *(bf16x8*)&Vs[strow * 64 + ((stslot ^ (strow & 7)) << 3)] = rv0;
    *(bf16x8*)&Vs[(strow + 32) * 64 + ((stslot ^ (strow & 7)) << 3)] = rv1;
    __syncthreads();
    if (kt + 1 < k1t) LOAD_KV(kt + 1);

    // fully-masked tile for this wave? -> skip compute
    if (kt * 64 > q0 + w * 32 + 31) continue;

    // ---- S^T = mfma(K, Q) ----
    f32x16 sA = {}, sB = {};
    __builtin_amdgcn_s_setprio(1);
#pragma unroll
    for (int c = 0; c < 4; ++c) {
      const int sl = ((2 * c + hi) ^ (qi & 7)) << 3;
      bf16x8 kfA = *(const bf16x8*)&Ks[qi * 64 + sl];
      bf16x8 kfB = *(const bf16x8*)&Ks[(qi + 32) * 64 + sl];
      bf16x8 qf = (c == 0) ? qb0 : (c == 1) ? qb1 : (c == 2) ? qb2 : qb3;
      sA = __builtin_amdgcn_mfma_f32_32x32x16_bf16(kfA, qf, sA, 0, 0, 0);
      sB = __builtin_amdgcn_mfma_f32_32x32x16_bf16(kfB, qf, sB, 0, 0, 0);
    }
    __builtin_amdgcn_s_setprio(0);

    // ---- causal mask (only near the diagonal) ----
    if (kt * 64 + 63 > q0 + w * 32) {
      const int qg = qrow;
#pragma unroll
      for (int r = 0; r < 16; ++r) {
        const int kl = (r & 3) + 8 * (r >> 2) + 4 * hi;
        if (kt * 64 + kl > qg) sA[r] = -INFINITY;
        if (kt * 64 + 32 + kl > qg) sB[r] = -INFINITY;
      }
    }

    // ---- online softmax: tree max, defer-max, exp, tree sum ----
    float tm[16];
#pragma unroll
    for (int r = 0; r < 16; ++r) tm[r] = fmaxf(sA[r], sB[r]);
#pragma unroll
    for (int s = 8; s >= 1; s >>= 1)
#pragma unroll
      for (int r = 0; r < s; ++r) tm[r] = fmaxf(tm[r], tm[r + s]);
    const float pm = fmaxf(tm[0], __shfl_xor(tm[0], 32));

    // defer-max (T13): only rescale when max grew by > 8
    if (!__all(pm <= m_r + 8.f)) {
      const float mnew = fmaxf(m_r, pm);
      const float corr = __expf(m_r - mnew);
      l_r *= corr;
#pragma unroll
      for (int r = 0; r < 16; ++r) { oA[r] *= corr; oB[r] *= corr; }
      m_r = mnew;
    }

#pragma unroll
    for (int r = 0; r < 16; ++r) sA[r] = __expf(sA[r] - m_r);
#pragma unroll
    for (int r = 0; r < 16; ++r) sB[r] = __expf(sB[r] - m_r);

    float ts[16];
#pragma unroll
    for (int r = 0; r < 16; ++r) ts[r] = sA[r] + sB[r];
#pragma unroll
    for (int s = 8; s >= 1; s >>= 1)
#pragma unroll
      for (int r = 0; r < s; ++r) ts[r] += ts[r + s];
    l_r += ts[0];

    // ---- P^T fragments ----
    bf16x8 pf0 = pk_swap8(sA[0], sA[1], sA[2], sA[3], sA[4], sA[5], sA[6], sA[7]);
    bf16x8 pf1 = pk_swap8(sA[8], sA[9], sA[10], sA[11], sA[12], sA[13], sA[14], sA[15]);
    bf16x8 pf2 = pk_swap8(sB[0], sB[1], sB[2], sB[3], sB[4], sB[5], sB[6], sB[7]);
    bf16x8 pf3 = pk_swap8(sB[8], sB[9], sB[10], sB[11], sB[12], sB[13], sB[14], sB[15]);

    // ---- O^T += mfma(V^T, P^T) ----
    __builtin_amdgcn_s_setprio(1);
#pragma unroll
    for (int c = 0; c < 4; ++c) {
      const int sl = ((2 * c + hi) ^ (qi & 7)) << 3;
      bf16x8 vfA = *(const bf16x8*)&Vs[qi * 64 + sl];
      bf16x8 vfB = *(const bf16x8*)&Vs[(qi + 32) * 64 + sl];
      bf16x8 pf = (c == 0) ? pf0 : (c == 1) ? pf1 : (c == 2) ? pf2 : pf3;
      oA = __builtin_amdgcn_mfma_f32_32x32x16_bf16(vfA, pf, oA, 0, 0, 0);
      oB = __builtin_amdgcn_mfma_f32_32x32x16_bf16(vfB, pf, oB, 0, 0, 0);
    }
    __builtin_amdgcn_s_setprio(0);
  }
#undef LOAD_KV

  // ---- epilogue ----
  const float lt = l_r + __shfl_xor(l_r, 32);
  const float inv = 1.f / lt;
#pragma unroll
  for (int r = 0; r < 16; ++r) { oA[r] *= inv; oB[r] *= inv; }

  bf16x8 e0 = pk_swap8(oA[0], oA[1], oA[2], oA[3], oA[4], oA[5], oA[6], oA[7]);
  bf16x8 e1 = pk_swap8(oA[8], oA[9], oA[10], oA[11], oA[12], oA[13], oA[14], oA[15]);
  bf16x8 e2 = pk_swap8(oB[0], oB[1], oB[2], oB[3], oB[4], oB[5], oB[6], oB[7]);
  bf16x8 e3 = pk_swap8(oB[8], oB[9], oB[10], oB[11], oB[12], oB[13], oB[14], oB[15]);

  if (slot < 0) {
    bf16* ob = &out[(size_t)qrow * EMBED + h * HDIM];
    *(bf16x8*)(ob + hi * 8) = e0;
    *(bf16x8*)(ob + 16 + hi * 8) = e1;
    *(bf16x8*)(ob + 32 + hi * 8) = e2;
    *(bf16x8*)(ob + 48 + hi * 8) = e3;
  } else {
    const int idx = ((qtb - 16) * 2 + slot) * 16 + h;
    const int lr = w * 32 + qi;
    bf16* pb = &partO[((size_t)idx * 128 + lr) * 64];
    *(bf16x8*)(pb + hi * 8) = e0;
    *(bf16x8*)(pb + 16 + hi * 8) = e1;
    *(bf16x8*)(pb + 32 + hi * 8) = e2;
    *(bf16x8*)(pb + 48 + hi * 8) = e3;
    if (hi == 0) partML[idx * 128 + lr] = make_float2(m_r, lt);
  }
}

// ---------------------------------------------------------------------------
// Merge the two kv-split partials for qtb in [16,32).
// Grid (16, HEADS), 256 threads; thread -> (row = tid>>1, d-half = (tid&1)*32).
// ---------------------------------------------------------------------------
__global__ __launch_bounds__(256) void merge_partials(
    const bf16* __restrict__ partO, const float2* __restrict__ partML,
    bf16* __restrict__ out) {
  const int qtb = 16 + blockIdx.x;
  const int h = blockIdx.y;
  const int tid = threadIdx.x;
  const int r = tid >> 1;
  const int dh = (tid & 1) * 32;
  const int idx0 = ((qtb - 16) * 2 + 0) * 16 + h;
  const int idx1 = idx0 + 16;
  const float2 ml0 = partML[idx0 * 128 + r];
  const float2 ml1 = partML[idx1 * 128 + r];
  const float m = fmaxf(ml0.x, ml1.x);
  float w0 = ml0.y * __expf(ml0.x - m);
  float w1 = ml1.y * __expf(ml1.x - m);
  const float inv = 1.f / (w0 + w1);
  w0 *= inv; w1 *= inv;
  const bf16* p0 = &partO[((size_t)idx0 * 128 + r) * 64 + dh];
  const bf16* p1 = &partO[((size_t)idx1 * 128 + r) * 64 + dh];
  bf16* ob = &out[(size_t)(qtb * 128 + r) * EMBED + h * HDIM + dh];
#pragma unroll
  for (int c = 0; c < 4; ++c) {
    bf16x8 a = *(const bf16x8*)(p0 + c * 8);
    bf16x8 b = *(const bf16x8*)(p1 + c * 8);
    bf16x8 o;
#pragma unroll
    for (int j = 0; j < 8; ++j)
      o[j] = (bf16)(w0 * (float)a[j] + w1 * (float)b[j]);
    *(bf16x8*)(ob + c * 8) = o;
  }
}

// ---------------------------------------------------------------------------
extern "C" void kernel_launch(void* const* d_in, const int* in_sizes, int n_in,
                              void* d_out, int out_size, void* d_ws, size_t ws_size,
                              hipStream_t stream) {
  const float* x     = (const float*)d_in[0];
  const float* W_qkv = (const float*)d_in[1];
  const float* b_qkv = (const float*)d_in[2];
  const float* W_out = (const float*)d_in[3];
  const float* b_out = (const float*)d_in[4];
  float* out = (float*)d_out;

  char* ws = (char*)d_ws;
  const size_t MB = 1024 * 1024;
  bf16* x_bf   = (bf16*)(ws + 0);        // 8 MB  [4096][1024]; dead after QKV gemm
  bf16* WqkvT  = (bf16*)(ws + 8 * MB);   // 6 MB; dead after QKV gemm
  bf16* WoutT  = (bf16*)(ws + 14 * MB);  // 2 MB
  bf16* qkvb   = (bf16*)(ws + 16 * MB);  // 24 MB [4096][3072]
  bf16* vT     = (bf16*)(ws + 40 * MB);  // 8 MB  [1024][4096]
  bf16* attn_o = (bf16*)(ws + 48 * MB);  // 8 MB  [4096][1024]
  // kv-split partials reuse dead regions:
  bf16*   partO  = (bf16*)(ws + 0);      // 512 x 128 x 64 bf16 = 8 MB (over x_bf)
  float2* partML = (float2*)(ws + 8 * MB);  // 512 x 128 float2 = 512 KB (over WqkvT)

  f32_to_bf16<<<(T_SEQ * EMBED) / (256 * 8), 256, 0, stream>>>(x, x_bf, T_SEQ * EMBED);
  transpose_f32_bf16<<<dim3(3 * EMBED / 32, EMBED / 32), 256, 0, stream>>>(
      W_qkv, WqkvT, EMBED, 3 * EMBED);
  transpose_f32_bf16<<<dim3(EMBED / 32, EMBED / 32), 256, 0, stream>>>(
      W_out, WoutT, EMBED, EMBED);

  gemm_bt_bias<false><<<dim3(3 * EMBED / 128, T_SEQ / 128), 256, 0, stream>>>(
      x_bf, WqkvT, b_qkv, qkvb, T_SEQ, 3 * EMBED, EMBED);

  transpose_v<<<dim3(T_SEQ / 64, HEADS), 256, 0, stream>>>(qkvb, vT);

  flash_attn_mfma<<<dim3(48, HEADS), 256, 0, stream>>>(qkvb, vT, attn_o, partO, partML);
  merge_partials<<<dim3(16, HEADS), 256, 0, stream>>>(partO, partML, attn_o);

  gemm_bt_bias<true><<<dim3(EMBED / 128, T_SEQ / 128), 256, 0, stream>>>(
      attn_o, WoutT, b_out, out, T_SEQ, EMBED, EMBED);
}

// Round 6
// 162.707 us; speedup vs baseline: 26.5627x; 1.0763x over previous
//
#include <hip/hip_runtime.h>
#include <hip/hip_bf16.h>
#include <math.h>

#define EMBED 1024
#define HEADS 16
#define HDIM 64
#define T_SEQ 4096

typedef __bf16 bf16;
typedef bf16 bf16x8 __attribute__((ext_vector_type(8)));
typedef float f32x4 __attribute__((ext_vector_type(4)));
typedef float f32x16 __attribute__((ext_vector_type(16)));

// ---------------------------------------------------------------------------
// fp32 -> bf16 elementwise (n % 8 == 0)
// ---------------------------------------------------------------------------
__global__ __launch_bounds__(256) void f32_to_bf16(
    const float* __restrict__ in, bf16* __restrict__ out, int n) {
  int i = (blockIdx.x * 256 + threadIdx.x) * 8;
  if (i >= n) return;
  float4 a = *(const float4*)&in[i];
  float4 b = *(const float4*)&in[i + 4];
  bf16x8 o;
  o[0] = (bf16)a.x; o[1] = (bf16)a.y; o[2] = (bf16)a.z; o[3] = (bf16)a.w;
  o[4] = (bf16)b.x; o[5] = (bf16)b.y; o[6] = (bf16)b.z; o[7] = (bf16)b.w;
  *(bf16x8*)&out[i] = o;
}

// ---------------------------------------------------------------------------
// Transpose fp32 [rows][cols] -> bf16 [cols][rows].
// ---------------------------------------------------------------------------
__global__ __launch_bounds__(256) void transpose_f32_bf16(
    const float* __restrict__ in, bf16* __restrict__ out, int rows, int cols) {
  __shared__ bf16 t[32][33];
  const int c0 = blockIdx.x * 32, r0 = blockIdx.y * 32;
  const int tx = threadIdx.x & 31, ty = threadIdx.x >> 5;
#pragma unroll
  for (int i = 0; i < 4; ++i)
    t[ty + 8 * i][tx] = (bf16)in[(size_t)(r0 + ty + 8 * i) * cols + c0 + tx];
  __syncthreads();
#pragma unroll
  for (int i = 0; i < 4; ++i)
    out[(size_t)(c0 + ty + 8 * i) * rows + r0 + tx] = t[tx][ty + 8 * i];
}

// ---------------------------------------------------------------------------
// Transpose V part of qkv into vT [H*64][T].
// ---------------------------------------------------------------------------
__global__ __launch_bounds__(256) void transpose_v(
    const bf16* __restrict__ qkvb, bf16* __restrict__ vT) {
  __shared__ bf16 t[64][65];
  const int h = blockIdx.y;
  const int t0 = blockIdx.x * 64;
  const int tx = threadIdx.x & 63, ty = threadIdx.x >> 6;
#pragma unroll
  for (int i = 0; i < 16; ++i)
    t[ty + 4 * i][tx] =
        qkvb[(size_t)(t0 + ty + 4 * i) * (3 * EMBED) + 2 * EMBED + h * HDIM + tx];
  __syncthreads();
#pragma unroll
  for (int i = 0; i < 16; ++i)
    vT[((size_t)h * HDIM + ty + 4 * i) * T_SEQ + t0 + tx] = t[tx][ty + 4 * i];
}

// ---------------------------------------------------------------------------
// bf16 MFMA GEMM:  C[M][N] = A[M][K] @ BT[N][K]^T + bias[N]   (unchanged)
// ---------------------------------------------------------------------------
template <bool OUT_F32>
__global__ __launch_bounds__(256) void gemm_bt_bias(
    const bf16* __restrict__ A, const bf16* __restrict__ BT,
    const float* __restrict__ bias, void* __restrict__ Cout,
    int M, int N, int K) {
  __shared__ __align__(16) bf16 As[128][40];
  __shared__ __align__(16) bf16 Bs[128][40];
  const int tid = threadIdx.x;
  const int lane = tid & 63;
  const int w = tid >> 6;
  const int wr = w >> 1, wc = w & 1;
  const int l16 = lane & 15, lq = lane >> 4;
  const int brow = blockIdx.y * 128;
  const int bcol = blockIdx.x * 128;

  f32x4 acc[4][4] = {};

  const int sr = tid >> 2;
  const int sc = (tid & 3) * 8;

  bf16x8 ra0, ra1, rb0, rb1;
#define LOAD_REGS(k0)                                                     \
  {                                                                       \
    ra0 = *(const bf16x8*)&A[(size_t)(brow + sr) * K + (k0) + sc];        \
    ra1 = *(const bf16x8*)&A[(size_t)(brow + sr + 64) * K + (k0) + sc];   \
    rb0 = *(const bf16x8*)&BT[(size_t)(bcol + sr) * K + (k0) + sc];       \
    rb1 = *(const bf16x8*)&BT[(size_t)(bcol + sr + 64) * K + (k0) + sc];  \
  }

  LOAD_REGS(0);
  for (int k0 = 0; k0 < K; k0 += 32) {
    __syncthreads();
    *(bf16x8*)&As[sr][sc] = ra0;
    *(bf16x8*)&As[sr + 64][sc] = ra1;
    *(bf16x8*)&Bs[sr][sc] = rb0;
    *(bf16x8*)&Bs[sr + 64][sc] = rb1;
    __syncthreads();
    if (k0 + 32 < K) LOAD_REGS(k0 + 32);

    bf16x8 af[4], bfr[4];
#pragma unroll
    for (int m = 0; m < 4; ++m)
      af[m] = *(const bf16x8*)&As[wr * 64 + m * 16 + l16][lq * 8];
#pragma unroll
    for (int n = 0; n < 4; ++n)
      bfr[n] = *(const bf16x8*)&Bs[wc * 64 + n * 16 + l16][lq * 8];
#pragma unroll
    for (int m = 0; m < 4; ++m)
#pragma unroll
      for (int n = 0; n < 4; ++n)
        acc[m][n] =
            __builtin_amdgcn_mfma_f32_16x16x32_bf16(af[m], bfr[n], acc[m][n], 0, 0, 0);
  }
#undef LOAD_REGS

#pragma unroll
  for (int m = 0; m < 4; ++m) {
    const int row = brow + wr * 64 + m * 16 + lq * 4;
#pragma unroll
    for (int n = 0; n < 4; ++n) {
      const int col = bcol + wc * 64 + n * 16 + l16;
      const float bv = bias[col];
#pragma unroll
      for (int r2 = 0; r2 < 4; ++r2) {
        float v = acc[m][n][r2] + bv;
        if (OUT_F32)
          ((float*)Cout)[(size_t)(row + r2) * N + col] = v;
        else
          ((bf16*)Cout)[(size_t)(row + r2) * N + col] = (bf16)v;
      }
    }
  }
}

// ---------------------------------------------------------------------------
// cvt_pk + permlane32_swap packing helper.
// ---------------------------------------------------------------------------
__device__ __forceinline__ bf16x8 pk_swap8(float a0, float a1, float a2, float a3,
                                           float a4, float a5, float a6, float a7) {
  unsigned W0, W1, W2, W3;
  asm("v_cvt_pk_bf16_f32 %0, %1, %2" : "=v"(W0) : "v"(a0), "v"(a1));
  asm("v_cvt_pk_bf16_f32 %0, %1, %2" : "=v"(W1) : "v"(a2), "v"(a3));
  asm("v_cvt_pk_bf16_f32 %0, %1, %2" : "=v"(W2) : "v"(a4), "v"(a5));
  asm("v_cvt_pk_bf16_f32 %0, %1, %2" : "=v"(W3) : "v"(a6), "v"(a7));
  asm("v_permlane32_swap_b32 %0, %1" : "+v"(W0), "+v"(W2));
  asm("v_permlane32_swap_b32 %0, %1" : "+v"(W1), "+v"(W3));
  union { unsigned u[4]; bf16x8 v; } r;
  r.u[0] = W0; r.u[1] = W1; r.u[2] = W2; r.u[3] = W3;
  return r.v;
}

// ---------------------------------------------------------------------------
// Job decode: per head, 80 jobs.
//   job 0..7   : qtb = job, direct (1 part, whole kv range)
//   job 8..23  : qtb = 8+(j-8)/2,  np=2, part=(j-8)%2
//   job 24..47 : qtb = 16+(j-24)/3, np=3, part=(j-24)%3
//   job 48..79 : qtb = 24+(j-48)/4, np=4, part=(j-48)%4
// Part p of nt tiles split np ways: even sizes (nt/np, remainder spread).
// Partial slot (per head, split jobs only, 72 slots):
//   qtb 8..15: (qtb-8)*2+part ; 16..23: 16+(qtb-16)*3+part ; 24..31: 40+(qtb-24)*4+part
// Global slot = h*72 + local. Slots 0..1023 live in d_out (16 KB each, exactly
// fills the 16 MB output buffer, rewritten by the final GEMM), 1024..1151 in ws.
// ---------------------------------------------------------------------------
__global__ __launch_bounds__(256) void flash_attn_mfma(
    const bf16* __restrict__ qkvb, const bf16* __restrict__ vT,
    bf16* __restrict__ out, bf16* __restrict__ partO_main,
    bf16* __restrict__ partO_ovf, float2* __restrict__ partML) {
  const int h = blockIdx.y;
  const int job = 79 - (int)blockIdx.x;  // big jobs first
  int qtb, np, part;
  if (job < 8)       { qtb = job;                np = 1; part = 0; }
  else if (job < 24) { qtb = 8 + ((job - 8) >> 1);  np = 2; part = (job - 8) & 1; }
  else if (job < 48) { int t = job - 24; qtb = 16 + t / 3; np = 3; part = t - (t / 3) * 3; }
  else               { int t = job - 48; qtb = 24 + (t >> 2); np = 4; part = t & 3; }
  const int nt = 2 * qtb + 2;
  const int bsz = nt / np, rem = nt % np;
  const int k0t = part * bsz + min(part, rem);
  const int k1t = k0t + bsz + (part < rem ? 1 : 0);

  int lslot = -1;
  if (np > 1) {
    if (qtb < 16)      lslot = (qtb - 8) * 2 + part;
    else if (qtb < 24) lslot = 16 + (qtb - 16) * 3 + part;
    else               lslot = 40 + (qtb - 24) * 4 + part;
  }

  const int q0 = qtb * 128;
  const int tid = threadIdx.x;
  const int lane = tid & 63;
  const int w = tid >> 6;
  const int qi = lane & 31;   // q index within wave tile
  const int hi = lane >> 5;   // k-half selector

  __shared__ __align__(16) bf16 Ks[64 * 64];  // [key][d], swizzled
  __shared__ __align__(16) bf16 Vs[64 * 64];  // [d][key], swizzled

  const int qrow = q0 + w * 32 + qi;

  // Q B-fragments, pre-scaled by 0.125 (exact in bf16)
  bf16x8 qb0, qb1, qb2, qb3;
  {
    const bf16* qp = &qkvb[(size_t)qrow * (3 * EMBED) + h * HDIM + hi * 8];
    qb0 = *(const bf16x8*)(qp + 0);
    qb1 = *(const bf16x8*)(qp + 16);
    qb2 = *(const bf16x8*)(qp + 32);
    qb3 = *(const bf16x8*)(qp + 48);
#pragma unroll
    for (int j = 0; j < 8; ++j) {
      qb0[j] = (bf16)((float)qb0[j] * 0.125f);
      qb1[j] = (bf16)((float)qb1[j] * 0.125f);
      qb2[j] = (bf16)((float)qb2[j] * 0.125f);
      qb3[j] = (bf16)((float)qb3[j] * 0.125f);
    }
  }

  f32x16 oA = {}, oB = {};
  float m_r = -INFINITY, l_r = 0.f;

  const int strow = tid >> 3;
  const int stslot = tid & 7;

  bf16x8 rk0, rk1, rv0, rv1;
#define LOAD_KV(kt)                                                                 \
  {                                                                                 \
    rk0 = *(const bf16x8*)&qkvb[(size_t)((kt) * 64 + strow) * (3 * EMBED) + EMBED + \
                                h * HDIM + stslot * 8];                             \
    rk1 = *(const bf16x8*)&qkvb[(size_t)((kt) * 64 + strow + 32) * (3 * EMBED) +    \
                                EMBED + h * HDIM + stslot * 8];                     \
    rv0 = *(const bf16x8*)&vT[((size_t)h * HDIM + strow) * T_SEQ + (kt) * 64 +      \
                              stslot * 8];                                          \
    rv1 = *(const bf16x8*)&vT[((size_t)h * HDIM + strow + 32) * T_SEQ + (kt) * 64 + \
                              stslot * 8];                                          \
  }

  LOAD_KV(k0t);
  for (int kt = k0t; kt < k1t; ++kt) {
    __syncthreads();
    *(bf16x8*)&Ks[strow * 64 + ((stslot ^ (strow & 7)) << 3)] = rk0;
    *(bf16x8*)&Ks[(strow + 32) * 64 + ((stslot ^ (strow & 7)) << 3)] = rk1;
    *(bf16x8*)&Vs[strow * 64 + ((stslot ^ (strow & 7)) << 3)] = rv0;
    *(bf16x8*)&Vs[(strow + 32) * 64 + ((stslot ^ (strow & 7)) << 3)] = rv1;
    __syncthreads();
    if (kt + 1 < k1t) LOAD_KV(kt + 1);

    // fully-masked tile for this wave? -> skip compute
    if (kt * 64 > q0 + w * 32 + 31) continue;

    // ---- S^T = mfma(K, Q) ----
    f32x16 sA = {}, sB = {};
    __builtin_amdgcn_s_setprio(1);
#pragma unroll
    for (int c = 0; c < 4; ++c) {
      const int sl = ((2 * c + hi) ^ (qi & 7)) << 3;
      bf16x8 kfA = *(const bf16x8*)&Ks[qi * 64 + sl];
      bf16x8 kfB = *(const bf16x8*)&Ks[(qi + 32) * 64 + sl];
      bf16x8 qf = (c == 0) ? qb0 : (c == 1) ? qb1 : (c == 2) ? qb2 : qb3;
      sA = __builtin_amdgcn_mfma_f32_32x32x16_bf16(kfA, qf, sA, 0, 0, 0);
      sB = __builtin_amdgcn_mfma_f32_32x32x16_bf16(kfB, qf, sB, 0, 0, 0);
    }
    __builtin_amdgcn_s_setprio(0);

    // ---- causal mask (only near the diagonal) ----
    if (kt * 64 + 63 > q0 + w * 32) {
      const int qg = qrow;
#pragma unroll
      for (int r = 0; r < 16; ++r) {
        const int kl = (r & 3) + 8 * (r >> 2) + 4 * hi;
        if (kt * 64 + kl > qg) sA[r] = -INFINITY;
        if (kt * 64 + 32 + kl > qg) sB[r] = -INFINITY;
      }
    }

    // ---- online softmax: tree max, defer-max, exp, tree sum ----
    float tm[16];
#pragma unroll
    for (int r = 0; r < 16; ++r) tm[r] = fmaxf(sA[r], sB[r]);
#pragma unroll
    for (int s = 8; s >= 1; s >>= 1)
#pragma unroll
      for (int r = 0; r < s; ++r) tm[r] = fmaxf(tm[r], tm[r + s]);
    const float pm = fmaxf(tm[0], __shfl_xor(tm[0], 32));

    // defer-max (T13): only rescale when max grew by > 8
    if (!__all(pm <= m_r + 8.f)) {
      const float mnew = fmaxf(m_r, pm);
      const float corr = __expf(m_r - mnew);
      l_r *= corr;
#pragma unroll
      for (int r = 0; r < 16; ++r) { oA[r] *= corr; oB[r] *= corr; }
      m_r = mnew;
    }

#pragma unroll
    for (int r = 0; r < 16; ++r) sA[r] = __expf(sA[r] - m_r);
#pragma unroll
    for (int r = 0; r < 16; ++r) sB[r] = __expf(sB[r] - m_r);

    float ts[16];
#pragma unroll
    for (int r = 0; r < 16; ++r) ts[r] = sA[r] + sB[r];
#pragma unroll
    for (int s = 8; s >= 1; s >>= 1)
#pragma unroll
      for (int r = 0; r < s; ++r) ts[r] += ts[r + s];
    l_r += ts[0];

    // ---- P^T fragments ----
    bf16x8 pf0 = pk_swap8(sA[0], sA[1], sA[2], sA[3], sA[4], sA[5], sA[6], sA[7]);
    bf16x8 pf1 = pk_swap8(sA[8], sA[9], sA[10], sA[11], sA[12], sA[13], sA[14], sA[15]);
    bf16x8 pf2 = pk_swap8(sB[0], sB[1], sB[2], sB[3], sB[4], sB[5], sB[6], sB[7]);
    bf16x8 pf3 = pk_swap8(sB[8], sB[9], sB[10], sB[11], sB[12], sB[13], sB[14], sB[15]);

    // ---- O^T += mfma(V^T, P^T) ----
    __builtin_amdgcn_s_setprio(1);
#pragma unroll
    for (int c = 0; c < 4; ++c) {
      const int sl = ((2 * c + hi) ^ (qi & 7)) << 3;
      bf16x8 vfA = *(const bf16x8*)&Vs[qi * 64 + sl];
      bf16x8 vfB = *(const bf16x8*)&Vs[(qi + 32) * 64 + sl];
      bf16x8 pf = (c == 0) ? pf0 : (c == 1) ? pf1 : (c == 2) ? pf2 : pf3;
      oA = __builtin_amdgcn_mfma_f32_32x32x16_bf16(vfA, pf, oA, 0, 0, 0);
      oB = __builtin_amdgcn_mfma_f32_32x32x16_bf16(vfB, pf, oB, 0, 0, 0);
    }
    __builtin_amdgcn_s_setprio(0);
  }
#undef LOAD_KV

  // ---- epilogue ----
  const float lt = l_r + __shfl_xor(l_r, 32);
  const float inv = lt > 0.f ? 1.f / lt : 0.f;
#pragma unroll
  for (int r = 0; r < 16; ++r) { oA[r] *= inv; oB[r] *= inv; }

  bf16x8 e0 = pk_swap8(oA[0], oA[1], oA[2], oA[3], oA[4], oA[5], oA[6], oA[7]);
  bf16x8 e1 = pk_swap8(oA[8], oA[9], oA[10], oA[11], oA[12], oA[13], oA[14], oA[15]);
  bf16x8 e2 = pk_swap8(oB[0], oB[1], oB[2], oB[3], oB[4], oB[5], oB[6], oB[7]);
  bf16x8 e3 = pk_swap8(oB[8], oB[9], oB[10], oB[11], oB[12], oB[13], oB[14], oB[15]);

  if (lslot < 0) {
    bf16* ob = &out[(size_t)qrow * EMBED + h * HDIM];
    *(bf16x8*)(ob + hi * 8) = e0;
    *(bf16x8*)(ob + 16 + hi * 8) = e1;
    *(bf16x8*)(ob + 32 + hi * 8) = e2;
    *(bf16x8*)(ob + 48 + hi * 8) = e3;
  } else {
    const int gslot = h * 72 + lslot;
    bf16* base = (gslot < 1024)
                     ? (bf16*)((char*)partO_main + (size_t)gslot * 16384)
                     : (bf16*)((char*)partO_ovf + (size_t)(gslot - 1024) * 16384);
    const int lr = w * 32 + qi;
    bf16* pb = base + (size_t)lr * 64;
    *(bf16x8*)(pb + hi * 8) = e0;
    *(bf16x8*)(pb + 16 + hi * 8) = e1;
    *(bf16x8*)(pb + 32 + hi * 8) = e2;
    *(bf16x8*)(pb + 48 + hi * 8) = e3;
    if (hi == 0) partML[gslot * 128 + lr] = make_float2(m_r, lt);
  }
}

// ---------------------------------------------------------------------------
// Merge 2-4 kv-split partials for qtb in [8,32). Grid (24, HEADS), 256 thr.
// Thread -> (row = tid>>1, d-half = (tid&1)*32). Unrolled compile-time part
// indices (rule #20: no runtime-indexed register arrays).
// ---------------------------------------------------------------------------
__global__ __launch_bounds__(256) void merge_partials(
    const bf16* __restrict__ partO_main, const bf16* __restrict__ partO_ovf,
    const float2* __restrict__ partML, bf16* __restrict__ out) {
  const int qtb = 8 + blockIdx.x;
  const int h = blockIdx.y;
  int np, lbase;
  if (qtb < 16)      { np = 2; lbase = (qtb - 8) * 2; }
  else if (qtb < 24) { np = 3; lbase = 16 + (qtb - 16) * 3; }
  else               { np = 4; lbase = 40 + (qtb - 24) * 4; }
  const int gbase = h * 72 + lbase;
  const int r = threadIdx.x >> 1;
  const int dh = (threadIdx.x & 1) * 32;

  float mm = -INFINITY;
  float mv[4], lv[4];
#pragma unroll
  for (int p = 0; p < 4; ++p)
    if (p < np) {
      const float2 ml = partML[(gbase + p) * 128 + r];
      mv[p] = ml.x; lv[p] = ml.y;
      mm = fmaxf(mm, ml.x);
    }
  float wsum = 0.f, wgt[4];
#pragma unroll
  for (int p = 0; p < 4; ++p)
    if (p < np) {
      wgt[p] = lv[p] * __expf(mv[p] - mm);
      wsum += wgt[p];
    }
  const float inv = 1.f / wsum;
#pragma unroll
  for (int p = 0; p < 4; ++p)
    if (p < np) wgt[p] *= inv;

  const bf16* pp[4];
#pragma unroll
  for (int p = 0; p < 4; ++p)
    if (p < np) {
      const int gs = gbase + p;
      const bf16* base = (gs < 1024)
                             ? (const bf16*)((const char*)partO_main + (size_t)gs * 16384)
                             : (const bf16*)((const char*)partO_ovf + (size_t)(gs - 1024) * 16384);
      pp[p] = base + (size_t)r * 64 + dh;
    }

  bf16* ob = &out[(size_t)(qtb * 128 + r) * EMBED + h * HDIM + dh];
#pragma unroll
  for (int c = 0; c < 4; ++c) {
    float acc[8] = {0.f, 0.f, 0.f, 0.f, 0.f, 0.f, 0.f, 0.f};
#pragma unroll
    for (int p = 0; p < 4; ++p)
      if (p < np) {
        bf16x8 v = *(const bf16x8*)(pp[p] + c * 8);
#pragma unroll
        for (int j = 0; j < 8; ++j) acc[j] += wgt[p] * (float)v[j];
      }
    bf16x8 o;
#pragma unroll
    for (int j = 0; j < 8; ++j) o[j] = (bf16)acc[j];
    *(bf16x8*)(ob + c * 8) = o;
  }
}

// ---------------------------------------------------------------------------
extern "C" void kernel_launch(void* const* d_in, const int* in_sizes, int n_in,
                              void* d_out, int out_size, void* d_ws, size_t ws_size,
                              hipStream_t stream) {
  const float* x     = (const float*)d_in[0];
  const float* W_qkv = (const float*)d_in[1];
  const float* b_qkv = (const float*)d_in[2];
  const float* W_out = (const float*)d_in[3];
  const float* b_out = (const float*)d_in[4];
  float* out = (float*)d_out;

  char* ws = (char*)d_ws;
  const size_t MB = 1024 * 1024;
  bf16* x_bf   = (bf16*)(ws + 0);        // 8 MB; dead after QKV gemm
  bf16* WqkvT  = (bf16*)(ws + 8 * MB);   // 6 MB; dead after QKV gemm
  bf16* WoutT  = (bf16*)(ws + 14 * MB);  // 2 MB (live to end)
  bf16* qkvb   = (bf16*)(ws + 16 * MB);  // 24 MB
  bf16* vT     = (bf16*)(ws + 40 * MB);  // 8 MB
  bf16* attn_o = (bf16*)(ws + 48 * MB);  // 8 MB
  // kv-split partials: slots 0..1023 in d_out (16 MB, exactly 1024 x 16 KB;
  // rewritten in full by the final GEMM), slots 1024..1151 over dead x_bf.
  bf16*   partO_main = (bf16*)d_out;
  bf16*   partO_ovf  = (bf16*)(ws + 0);
  float2* partML     = (float2*)(ws + 8 * MB);  // 1152*128*8B = 1.2 MB over WqkvT

  f32_to_bf16<<<(T_SEQ * EMBED) / (256 * 8), 256, 0, stream>>>(x, x_bf, T_SEQ * EMBED);
  transpose_f32_bf16<<<dim3(3 * EMBED / 32, EMBED / 32), 256, 0, stream>>>(
      W_qkv, WqkvT, EMBED, 3 * EMBED);
  transpose_f32_bf16<<<dim3(EMBED / 32, EMBED / 32), 256, 0, stream>>>(
      W_out, WoutT, EMBED, EMBED);

  gemm_bt_bias<false><<<dim3(3 * EMBED / 128, T_SEQ / 128), 256, 0, stream>>>(
      x_bf, WqkvT, b_qkv, qkvb, T_SEQ, 3 * EMBED, EMBED);

  transpose_v<<<dim3(T_SEQ / 64, HEADS), 256, 0, stream>>>(qkvb, vT);

  flash_attn_mfma<<<dim3(80, HEADS), 256, 0, stream>>>(qkvb, vT, attn_o, partO_main,
                                                       partO_ovf, partML);
  merge_partials<<<dim3(24, HEADS), 256, 0, stream>>>(partO_main, partO_ovf, partML,
                                                      attn_o);

  gemm_bt_bias<true><<<dim3(EMBED / 128, T_SEQ / 128), 256, 0, stream>>>(
      attn_o, WoutT, b_out, out, T_SEQ, EMBED, EMBED);
}